// Round 6
// baseline (224.790 us; speedup 1.0000x reference)
//
#include <hip/hip_runtime.h>

#define NN 40000
#define SS 16
#define CC 96
#define GG 12
#define NGRP 5000  // node groups of 8 (2 per wave x 4 waves)
#define SXP 104   // ushort stride for qkv transpose buffer: 208 B rows, 16B-aligned frag reads

typedef __attribute__((ext_vector_type(8))) short bf16x8;
typedef __attribute__((ext_vector_type(4))) float f32x4;

// float -> bf16 (RNE), raw 16-bit pattern (prep-path quality)
__device__ __forceinline__ short f2bf(float f) {
    union { float f; unsigned u; } c; c.f = f;
    unsigned r = (c.u + 0x7fffu + ((c.u >> 16) & 1u)) >> 16;
    return (short)r;
}
// pack two floats -> (bf16(hi)<<16)|bf16(lo) in ONE v_perm_b32 (+half-up rounding)
__device__ __forceinline__ unsigned pack2bf(float hi, float lo) {
    unsigned a = __float_as_uint(hi) + 0x8000u;
    unsigned b = __float_as_uint(lo) + 0x8000u;
    return __builtin_amdgcn_perm(a, b, 0x07060302u);
}
// single float -> bf16 (half-up, 2 ops)
__device__ __forceinline__ ushort f2bf_hu(float f) {
    return (ushort)((__float_as_uint(f) + 0x8000u) >> 16);
}
// bf16 (raw ushort) -> float: one shift
__device__ __forceinline__ float bf2f(ushort u) {
    return __uint_as_float(((unsigned)u) << 16);
}

// ---- DPP cross-lane within 16-lane rows (~2 cyc vs ~120 for ds_bpermute) ----
template<int CTRL>
__device__ __forceinline__ float dppf(float x) {
    int r = __builtin_amdgcn_mov_dpp(__float_as_int(x), CTRL, 0xF, 0xF, true);
    return __int_as_float(r);
}
__device__ __forceinline__ float row16_sum(float x) {
    x += dppf<0xB1>(x);    // quad_perm [1,0,3,2]
    x += dppf<0x4E>(x);    // quad_perm [2,3,0,1]
    x += dppf<0x141>(x);   // ROW_HALF_MIRROR
    x += dppf<0x140>(x);   // ROW_MIRROR
    return x;
}
__device__ __forceinline__ float row16_max(float x) {
    x = fmaxf(x, dppf<0xB1>(x));
    x = fmaxf(x, dppf<0x4E>(x));
    x = fmaxf(x, dppf<0x141>(x));
    x = fmaxf(x, dppf<0x140>(x));
    return x;
}

// job-range constants for prep
#define J_W3   27648            // 3 x 9216: Wq/Wk/Wv frags
#define J_P2   (J_W3 + 9216)    // Wp2 frags
#define J_W1   (J_P2 + 1536)    // Ww1 frags (padded to 16 cols)
#define J_WF   (J_W1 + 1536)    // Wfused frags (direct 96-dot)
#define J_CF   (J_WF + 12)      // cfused
#define J_S4   (J_CF + 4)       // s4 = A^T 1
#define J_G    (J_S4 + 16)      // G = A^T A
// grid = ceil(J_G/256) = 157

// ---------------- prep: all weight fragments + LN-stats, once ----------------
__global__ void prep_kernel(const float* __restrict__ Wq, const float* __restrict__ Wk,
                            const float* __restrict__ Wv, const float* __restrict__ Wp2,
                            const float* __restrict__ Ww1, const float* __restrict__ bp2,
                            const float* __restrict__ bw1, const float* __restrict__ Wp1,
                            const float* __restrict__ bp1,
                            ushort* __restrict__ fragQKV, ushort* __restrict__ fragP2,
                            ushort* __restrict__ fragW1, ushort* __restrict__ fragWf,
                            float* __restrict__ cfused, float* __restrict__ stats)
{
    const int job = blockIdx.x*256 + threadIdx.x;
    if (job < J_W3) {
        const int which = job / 9216, o = job % 9216;
        const float* W = (which == 0) ? Wq : (which == 1) ? Wk : Wv;
        const int pos = o >> 3, j = o & 7;
        const int lane = pos & 63, ntkb = pos >> 6;
        const int nt = ntkb / 3, kb = ntkb - nt*3;
        const int col = nt*16 + (lane & 15), krow = kb*32 + (lane >> 4)*8 + j;
        fragQKV[job] = (ushort)f2bf(W[krow*CC + col]);
    } else if (job < J_P2) {
        const int o = job - J_W3;
        const int pos = o >> 3, j = o & 7;
        const int lane = pos & 63, ntkb = pos >> 6;
        const int nt = ntkb / 3, kb = ntkb - nt*3;
        const int col = nt*16 + (lane & 15), krow = kb*32 + (lane >> 4)*8 + j;
        fragP2[o] = (ushort)f2bf(Wp2[krow*CC + col]);
    } else if (job < J_W1) {
        const int o = job - J_P2;
        const int pos = o >> 3, j = o & 7;
        const int lane = pos & 63, kb = pos >> 6;
        const int col = lane & 15, krow = kb*32 + (lane >> 4)*8 + j;
        fragW1[o] = (col < GG) ? (ushort)f2bf(Ww1[krow*GG + col]) : (ushort)0;
    } else if (job < J_WF) {
        const int o = job - J_W1;
        const int pos = o >> 3, j = o & 7;
        const int lane = pos & 63, kb = pos >> 6;
        const int col = lane & 15, krow = kb*32 + (lane >> 4)*8 + j;
        float s = 0.f;
        if (col < GG) for (int jj = 0; jj < CC; ++jj) s += Wp2[krow*CC + jj] * Ww1[jj*GG + col];
        fragWf[o] = (col < GG) ? (ushort)f2bf(s) : (ushort)0;
    } else if (job < J_CF) {
        const int g = job - J_WF;
        float s = bw1[g];
        for (int jj = 0; jj < CC; ++jj) s += bp2[jj] * Ww1[jj*GG + g];
        cfused[g] = s;
    } else if (job < J_S4) {
        const int d = job - J_CF;
        float s = 0.f;
        for (int c = 0; c < CC; ++c) s += (d < 3) ? Wp1[d*CC + c] : bp1[c];
        stats[d] = s;
    } else if (job < J_G) {
        const int o = job - J_S4, d1 = o >> 2, d2 = o & 3;
        float s = 0.f;
        for (int c = 0; c < CC; ++c) {
            const float a1 = (d1 < 3) ? Wp1[d1*CC + c] : bp1[c];
            const float a2 = (d2 < 3) ? Wp1[d2*CC + c] : bp1[c];
            s += a1*a2;
        }
        stats[4 + o] = s;
    }
}

// ---------------- Kernel A: q/k/v projections via MFMA, ONE tile per wave ----------------
// R14: val bf16. R15: qw1/kw1 outputs also bf16 (shrinks attn2's hot random footprint).
__global__ __launch_bounds__(256) void qkv_mfma(
    const float* __restrict__ q, const float* __restrict__ kx, const float* __restrict__ v,
    const float* __restrict__ bq, const float* __restrict__ gq, const float* __restrict__ betaq,
    const float* __restrict__ bk, const float* __restrict__ gk, const float* __restrict__ betak,
    const float* __restrict__ bv,
    const ushort* __restrict__ fragQKV, const ushort* __restrict__ fragW1,
    ushort* __restrict__ valout, ushort* __restrict__ qw1out, ushort* __restrict__ kw1out)
{
    __shared__ float sbias[CC], sg[CC], sbeta[CC];
    __shared__ __align__(16) ushort sx2[4][16*SXP];   // per-wave bf16 transpose buffer

    const int p = blockIdx.y;
    const float* X; const float* b;
    const float* g = nullptr; const float* beta = nullptr;
    if (p == 0)      { X = q;  b = bq; g = gq; beta = betaq; }
    else if (p == 1) { X = kx; b = bk; g = gk; beta = betak; }
    else             { X = v;  b = bv; }
    const bool has_ln = (p < 2);
    ushort* w1out = (p == 0) ? qw1out : kw1out;

    const int t = threadIdx.x;
    if (t < CC) {
        sbias[t] = b[t];
        if (has_ln) { sg[t] = g[t]; sbeta[t] = beta[t]; }
    }

    const int lane = t & 63, w = t >> 6;
    const int c16 = lane & 15, quad = lane >> 4;
    const ushort* fragW = fragQKV + p*9216;

    bf16x8 Ww1f[3];
    if (has_ln) {
        #pragma unroll
        for (int kb = 0; kb < 3; ++kb) {
            union { bf16x8 v; uint4 u; } wu;
            wu.u = ((const uint4*)fragW1)[kb*64 + lane];
            Ww1f[kb] = wu.v;
        }
    }

    __syncthreads();

    const f32x4 zero4 = {0.f, 0.f, 0.f, 0.f};
    ushort* sxw = sx2[w];
    const int tile = blockIdx.x*4 + w;     // exactly 2500 tiles
    const int row0 = tile * 16;

    const float* xr = X + (size_t)(row0 + c16)*CC;
    bf16x8 Af[3];
    #pragma unroll
    for (int kb = 0; kb < 3; ++kb) {
        const float4 a0 = *(const float4*)(xr + kb*32 + quad*8);
        const float4 a1 = *(const float4*)(xr + kb*32 + quad*8 + 4);
        union { bf16x8 v; uint u[4]; } au;
        au.u[0] = pack2bf(a0.y, a0.x);
        au.u[1] = pack2bf(a0.w, a0.z);
        au.u[2] = pack2bf(a1.y, a1.x);
        au.u[3] = pack2bf(a1.w, a1.z);
        Af[kb] = au.v;
    }

    f32x4 acc[6];
    #pragma unroll
    for (int nt = 0; nt < 6; ++nt) acc[nt] = zero4;
    #pragma unroll
    for (int kb = 0; kb < 3; ++kb)
        #pragma unroll
        for (int nt = 0; nt < 6; ++nt) {
            const bf16x8 bf = *(const bf16x8*)(fragW + ((nt*3 + kb)*64 + lane)*8);
            acc[nt] = __builtin_amdgcn_mfma_f32_16x16x32_bf16(Af[kb], bf, acc[nt], 0, 0, 0);
        }

    #pragma unroll
    for (int nt = 0; nt < 6; ++nt) {
        const float bb = sbias[nt*16 + c16];
        #pragma unroll
        for (int r = 0; r < 4; ++r) acc[nt][r] += bb;
    }

    if (has_ln) {
        #pragma unroll
        for (int r = 0; r < 4; ++r) {
            float sum = 0.f, sq = 0.f;
            #pragma unroll
            for (int nt = 0; nt < 6; ++nt) { float x = acc[nt][r]; sum += x; sq += x*x; }
            sum = row16_sum(sum); sq = row16_sum(sq);
            const float mu  = sum * (1.f/96.f);
            const float var = sq * (1.f/96.f) - mu*mu;
            const float rs  = rsqrtf(var + 1e-5f);
            #pragma unroll
            for (int nt = 0; nt < 6; ++nt) {
                const int c = nt*16 + c16;
                acc[nt][r] = fmaxf((acc[nt][r] - mu)*rs*sg[c] + sbeta[c], 0.f);
            }
        }
        // C/D -> per-wave bf16 LDS -> direct A-frag readback (no repacking)
        #pragma unroll
        for (int nt = 0; nt < 6; ++nt)
            #pragma unroll
            for (int r = 0; r < 4; ++r)
                sxw[(quad*4 + r)*SXP + nt*16 + c16] = f2bf_hu(acc[nt][r]);

        f32x4 o = zero4;
        #pragma unroll
        for (int kb = 0; kb < 3; ++kb) {
            const bf16x8 aA = *(const bf16x8*)(sxw + c16*SXP + kb*32 + quad*8);
            o = __builtin_amdgcn_mfma_f32_16x16x32_bf16(aA, Ww1f[kb], o, 0, 0, 0);
        }
        if (c16 < GG) {
            #pragma unroll
            for (int r = 0; r < 4; ++r)
                w1out[(size_t)(row0 + quad*4 + r)*GG + c16] = (ushort)f2bf(o[r]);
        }
    } else {
        #pragma unroll
        for (int r = 0; r < 4; ++r)
            #pragma unroll
            for (int nt = 0; nt < 6; ++nt)
                valout[(size_t)(row0 + quad*4 + r)*CC + nt*16 + c16] = (ushort)f2bf(acc[nt][r]);
    }
}

// ---------------- Kernel B: grouped vector attention, persistent blocks ----------------
// R16 = R15 resubmitted (R15 bench was an infra failure, not a kernel verdict).
// R15: residency diagnosis — R14's byte cut (137->84 MB) barely moved time; occupancy
// stuck at 29% (9 waves/CU vs 16-wave VGPR cap) with 5000 short-lived blocks. Now:
// 1280 PERSISTENT blocks (5 x 256) grid-striding over 5000 groups: no ramp/tail,
// block-time variance smooths, sWp2f staging amortized 4x. Next group's refidx is
// prefetched during the current epilogue (cross-iteration pipeline). Loop-invariant
// sstats/gw/betaw/cfused hoisted to regs. kw1w/qw1w now bf16 (hot-footprint shrink).
// VGPR must stay <= 128 (occupancy cliff). LDS ~28 KB.
__global__ __launch_bounds__(256) void attn2(
    const float* __restrict__ xyz, const int* __restrict__ refidx,
    const float* __restrict__ gp,  const float* __restrict__ betap,
    const float* __restrict__ Wp1, const float* __restrict__ bp1,
    const float* __restrict__ bp2,
    const float* __restrict__ gw,  const float* __restrict__ betaw,
    const float* __restrict__ Ww2, const float* __restrict__ bw2,
    const float* __restrict__ cfused, const float* __restrict__ stats,
    const ushort* __restrict__ fragP2, const ushort* __restrict__ fragWf,
    const ushort* __restrict__ valw, const ushort* __restrict__ kw1w, const ushort* __restrict__ qw1w,
    float* __restrict__ out)
{
    __shared__ __align__(16) ushort sWp2f[9216];   // Wp2 B-frags, 18 KB
    __shared__ float4 sA[CC];                      // (Wp1 row0, row1, row2, bp1) per col
    __shared__ float2 sGB[CC];                     // (gp, betap) per col
    __shared__ float  sbp2[CC];
    __shared__ __align__(16) float sWw2T[GG*GG];   // Ww2 TRANSPOSED: [g'][g], 48B rows 16B-aligned
    __shared__ float  sgw[16], sbetaw[16], sbw2[16], scf[16];
    __shared__ float  sstats[20];
    __shared__ __align__(16) float ybuf[4][2][SS*GG]; // per wave, per node: yb then sw2 (aliased)

    const int t = threadIdx.x;
    if (t < CC) {
        sA[t]  = make_float4(Wp1[t], Wp1[CC + t], Wp1[2*CC + t], bp1[t]);
        sGB[t] = make_float2(gp[t], betap[t]);
        sbp2[t] = bp2[t];
    }
    if (t < GG*GG) {
        const int gr = t / GG, gc = t - gr*GG;     // Ww2[gr][gc]
        sWw2T[gc*GG + gr] = Ww2[t];
    }
    if (t < 16) {
        sgw[t]    = (t < GG) ? gw[t]     : 0.f;
        sbetaw[t] = (t < GG) ? betaw[t]  : 0.f;
        sbw2[t]   = (t < GG) ? bw2[t]    : 0.f;
        scf[t]    = (t < GG) ? cfused[t] : 0.f;
    }
    if (t < 20) sstats[t] = stats[t];
    for (int i = t; i < 1152; i += 256) ((uint4*)sWp2f)[i] = ((const uint4*)fragP2)[i];

    const int lane = t & 63, w = t >> 6;
    const int c16 = lane & 15, quad = lane >> 4;
    const int gcl = (c16 < GG) ? c16 : (GG-1);
    const float laneg = (c16 < GG) ? 1.f : 0.f;

    // Wfused B-frags in registers (one-time coalesced load, loop-invariant)
    bf16x8 Wff[3];
    #pragma unroll
    for (int kb = 0; kb < 3; ++kb) {
        union { bf16x8 v; uint4 u; } wu;
        wu.u = ((const uint4*)fragWf)[kb*64 + lane];
        Wff[kb] = wu.v;
    }

    __syncthreads();   // staging done; below is wave-synchronous

    // ---- loop-invariant LDS -> reg hoists ----
    const float st0 = sstats[0], st1 = sstats[1], st2 = sstats[2], st3 = sstats[3];
    float G_[16];
    #pragma unroll
    for (int i = 0; i < 16; ++i) G_[i] = sstats[4 + i];
    const float gwv = sgw[c16], bwv = sbetaw[c16], cf = scf[c16];

    const f32x4 zero4 = {0.f, 0.f, 0.f, 0.f};
    const int stride = (int)gridDim.x;

    // ---- prologue: prefetch first group's refidx ----
    int   id[2];  int4 rr[2];
    {
        const int n0p = blockIdx.x*8 + w*2;
        #pragma unroll
        for (int u = 0; u < 2; ++u) {
            id[u] = refidx[(size_t)(n0p + u)*SS + c16];
            rr[u] = *(const int4*)(refidx + (size_t)(n0p + u)*SS + quad*4);
        }
    }

    for (int grp = blockIdx.x; grp < NGRP; grp += stride) {
        const int n0 = grp*8 + w*2;   // two nodes per wave: n0, n0+1

        // ==== ISSUE GROUP 1 (oldest outstanding after refidx): static-address
        // loads consumed early (phases 2-4) — must be older than va in the FIFO.
        ushort qvu[2];
        #pragma unroll
        for (int u = 0; u < 2; ++u) qvu[u] = qw1w[(size_t)(n0 + u)*GG + gcl];
        float cxx[2], cxy[2], cxz[2];
        #pragma unroll
        for (int u = 0; u < 2; ++u) {
            cxx[u] = xyz[(size_t)(n0 + u)*3 + 0];
            cxy[u] = xyz[(size_t)(n0 + u)*3 + 1];
            cxz[u] = xyz[(size_t)(n0 + u)*3 + 2];
        }

        // ---- consume refidx (prefetched last iteration; latency already hidden) ----
        float mm[2]; int safe1[2];
        #pragma unroll
        for (int u = 0; u < 2; ++u) {
            mm[u]    = (id[u] >= 0) ? 1.f : 0.f;
            safe1[u] = (id[u] < 0) ? 0 : id[u];
        }
        int sid[2][4]; float mrg[2][4];
        #pragma unroll
        for (int u = 0; u < 2; ++u) {
            const int rv0 = rr[u].x, rv1 = rr[u].y, rv2 = rr[u].z, rv3 = rr[u].w;
            sid[u][0] = (rv0 < 0) ? 0 : rv0;  mrg[u][0] = (rv0 >= 0) ? laneg : 0.f;
            sid[u][1] = (rv1 < 0) ? 0 : rv1;  mrg[u][1] = (rv1 >= 0) ? laneg : 0.f;
            sid[u][2] = (rv2 < 0) ? 0 : rv2;  mrg[u][2] = (rv2 >= 0) ? laneg : 0.f;
            sid[u][3] = (rv3 < 0) ? 0 : rv3;  mrg[u][3] = (rv3 >= 0) ? laneg : 0.f;
        }

        // ==== ISSUE GROUP 2: refidx-dependent gathers consumed at phases 2-4 ====
        float sxx[2], sxy[2], sxz[2];
        #pragma unroll
        for (int u = 0; u < 2; ++u) {
            sxx[u] = xyz[(size_t)safe1[u]*3 + 0];
            sxy[u] = xyz[(size_t)safe1[u]*3 + 1];
            sxz[u] = xyz[(size_t)safe1[u]*3 + 2];
        }
        ushort kwu[2][4];
        #pragma unroll
        for (int u = 0; u < 2; ++u)
            #pragma unroll
            for (int r = 0; r < 4; ++r)
                kwu[u][r] = kw1w[(size_t)sid[u][r]*GG + gcl];

        // PIN: group 1/2 may not sink below va (would re-invert vmcnt order).
        __builtin_amdgcn_sched_barrier(0);

        // ==== ISSUE GROUP 3 (youngest): va gathers as raw bf16 ushort, ntp-major
        // matching the epilogue's FIFO consumption. Masked rows load garbage from
        // row 0 — harmless: their softmax weight is exactly 0.
        ushort va[3][2][2][4];
        #pragma unroll
        for (int ntp = 0; ntp < 3; ++ntp)
            #pragma unroll
            for (int h = 0; h < 2; ++h)
                #pragma unroll
                for (int u = 0; u < 2; ++u)
                    #pragma unroll
                    for (int r = 0; r < 4; ++r)
                        va[ntp][h][u][r] = valw[(size_t)sid[u][r]*CC + (2*ntp + h)*16 + c16];

        // ---- cross-iteration pipeline: prefetch NEXT group's refidx now; its
        // latency hides under phases 2-8. Clamped re-load of current group when
        // no next group exists (values unused).
        int idn[2]; int4 rrn[2];
        {
            const int grpn = (grp + stride < NGRP) ? (grp + stride) : grp;
            const int n0n = grpn*8 + w*2;
            #pragma unroll
            for (int u = 0; u < 2; ++u) {
                idn[u] = refidx[(size_t)(n0n + u)*SS + c16];
                rrn[u] = *(const int4*)(refidx + (size_t)(n0n + u)*SS + quad*4);
            }
        }

        // PIN: compute below may not hoist above; loads may not sink.
        __builtin_amdgcn_sched_barrier(0);

        // ---- px computed AFTER va issue: the xyz wait leaves va in flight ----
        float px[2], py[2], pz[2];
        #pragma unroll
        for (int u = 0; u < 2; ++u) {
            px[u] = (sxx[u] - cxx[u]) * mm[u];
            py[u] = (sxy[u] - cxy[u]) * mm[u];
            pz[u] = (sxz[u] - cxz[u]) * mm[u];
        }

        // ==== phase 2: analytic LN stats for both nodes (reg-resident consts) ====
        float muv[2], rsv[2];
        #pragma unroll
        for (int u = 0; u < 2; ++u) {
            muv[u] = (px[u]*st0 + py[u]*st1 + pz[u]*st2 + st3) * (1.f/96.f);
            const float p4[4] = {px[u], py[u], pz[u], 1.f};
            float e2 = 0.f;
            #pragma unroll
            for (int a = 0; a < 4; ++a) {
                float ta = 0.f;
                #pragma unroll
                for (int b2 = 0; b2 < 4; ++b2) ta = fmaf(G_[a*4 + b2], p4[b2], ta);
                e2 = fmaf(p4[a], ta, e2);
            }
            const float var = e2*(1.f/96.f) - muv[u]*muv[u];
            rsv[u] = rsqrtf(var + 1e-5f);
        }

        // ==== phase 3: t1A for both nodes; per-column consts loaded ONCE ====
        bf16x8 t1A[2][3];
        #pragma unroll
        for (int kb = 0; kb < 3; ++kb) {
            uint tw[2][4];
            #pragma unroll
            for (int jp = 0; jp < 4; ++jp) {
                const int c0 = kb*32 + quad*8 + jp*2, c1 = c0 + 1;
                const float4 aw0 = sA[c0], aw1 = sA[c1];
                const float2 gb0 = sGB[c0], gb1 = sGB[c1];
                #pragma unroll
                for (int u = 0; u < 2; ++u) {
                    const float x0 = fmaf(px[u], aw0.x, fmaf(py[u], aw0.y, fmaf(pz[u], aw0.z, aw0.w)));
                    const float x1 = fmaf(px[u], aw1.x, fmaf(py[u], aw1.y, fmaf(pz[u], aw1.z, aw1.w)));
                    const float t0 = fmaxf(fmaf((x0 - muv[u])*rsv[u], gb0.x, gb0.y), 0.f);
                    const float t1v = fmaxf(fmaf((x1 - muv[u])*rsv[u], gb1.x, gb1.y), 0.f);
                    tw[u][jp] = pack2bf(t1v, t0);
                }
            }
            #pragma unroll
            for (int u = 0; u < 2; ++u) {
                union { bf16x8 v; uint uu[4]; } tc;
                tc.uu[0] = tw[u][0]; tc.uu[1] = tw[u][1];
                tc.uu[2] = tw[u][2]; tc.uu[3] = tw[u][3];
                t1A[u][kb] = tc.v;
            }
        }

        // ==== phase 4: t2 = t1 @ Wfused (Wff in regs; va stays outstanding) ====
        f32x4 t2[2];
        #pragma unroll
        for (int u = 0; u < 2; ++u) t2[u] = zero4;
        #pragma unroll
        for (int kb = 0; kb < 3; ++kb)
            #pragma unroll
            for (int u = 0; u < 2; ++u)
                t2[u] = __builtin_amdgcn_mfma_f32_16x16x32_bf16(t1A[u][kb], Wff[kb], t2[u], 0, 0, 0);
        #pragma unroll
        for (int u = 0; u < 2; ++u) {
            const float qz = bf2f(qvu[u])*laneg;
            #pragma unroll
            for (int r = 0; r < 4; ++r)
                t2[u][r] += bf2f(kwu[u][r])*mrg[u][r] - qz + cf;
        }

        // ==== phase 5: LN over G=12 via DPP; both chains interleave ====
        #pragma unroll
        for (int u = 0; u < 2; ++u) {
            float* yb = ybuf[w][u];
            #pragma unroll
            for (int r = 0; r < 4; ++r) {
                const float x = t2[u][r];          // exact 0 on c16>=12 lanes
                const float s1 = row16_sum(x);
                const float s2 = row16_sum(x*x);
                const float mu2  = s1 * (1.f/12.f);
                const float var2 = s2 * (1.f/12.f) - mu2*mu2;
                const float rs2  = rsqrtf(var2 + 1e-5f);
                const float y    = fmaxf((x - mu2)*rs2*gwv + bwv, 0.f);
                if (c16 < GG) yb[(quad*4 + r)*GG + c16] = y;
            }
        }

        // ==== phase 6: w3 = y @ Ww2 + bw2; Ww2T rows loaded ONCE for both ====
        float w3v[2][3];
        {
            f32x4 yr[2][3];
            #pragma unroll
            for (int u = 0; u < 2; ++u) {
                yr[u][0] = *(const f32x4*)(ybuf[w][u] + c16*GG + 0);
                yr[u][1] = *(const f32x4*)(ybuf[w][u] + c16*GG + 4);
                yr[u][2] = *(const f32x4*)(ybuf[w][u] + c16*GG + 8);
            }
            #pragma unroll
            for (int gi = 0; gi < 3; ++gi) {
                const int gpp = quad + gi*4;
                const f32x4 wa = *(const f32x4*)(sWw2T + gpp*GG + 0);
                const f32x4 wb = *(const f32x4*)(sWw2T + gpp*GG + 4);
                const f32x4 wc = *(const f32x4*)(sWw2T + gpp*GG + 8);
                const float bb = sbw2[gpp];
                #pragma unroll
                for (int u = 0; u < 2; ++u) {
                    float a2 = bb;
                    #pragma unroll
                    for (int j = 0; j < 4; ++j) a2 = fmaf(yr[u][0][j], wa[j], a2);
                    #pragma unroll
                    for (int j = 0; j < 4; ++j) a2 = fmaf(yr[u][1][j], wb[j], a2);
                    #pragma unroll
                    for (int j = 0; j < 4; ++j) a2 = fmaf(yr[u][2][j], wc[j], a2);
                    w3v[u][gi] = a2;
                }
            }
        }

        // ==== phase 7: softmax over s (DPP) + transposed store sw2[g'][s] ====
        #pragma unroll
        for (int u = 0; u < 2; ++u) {
            #pragma unroll
            for (int gi = 0; gi < 3; ++gi) {
                const float mx = row16_max(w3v[u][gi]);
                const float e  = __expf(w3v[u][gi] - mx);
                const float tot = row16_sum(e);
                w3v[u][gi] = e * __builtin_amdgcn_rcpf(tot) * mm[u];
            }
            float* sw2 = ybuf[w][u];   // aliased with yb: all yb reads above done
            #pragma unroll
            for (int gi = 0; gi < 3; ++gi)
                sw2[(quad + 4*gi)*16 + c16] = w3v[u][gi];
        }

        // ==== phase 8: merged epilogue; va consumed in FIFO (ntp, h, u) order ====
        #pragma unroll
        for (int ntp = 0; ntp < 3; ++ntp) {
            const int nt0 = 2*ntp, nt1 = 2*ntp + 1;
            f32x4 pa[2], pb[2];
            #pragma unroll
            for (int u = 0; u < 2; ++u) { pa[u] = zero4; pb[u] = zero4; }
            #pragma unroll
            for (int kb = 0; kb < 3; ++kb) {
                const bf16x8 bfa = *(const bf16x8*)(sWp2f + ((nt0*3 + kb)*64 + lane)*8);
                const bf16x8 bfb = *(const bf16x8*)(sWp2f + ((nt1*3 + kb)*64 + lane)*8);
                #pragma unroll
                for (int u = 0; u < 2; ++u) {
                    pa[u] = __builtin_amdgcn_mfma_f32_16x16x32_bf16(t1A[u][kb], bfa, pa[u], 0, 0, 0);
                    pb[u] = __builtin_amdgcn_mfma_f32_16x16x32_bf16(t1A[u][kb], bfb, pb[u], 0, 0, 0);
                }
            }
            #pragma unroll
            for (int h = 0; h < 2; ++h) {
                const int nt = 2*ntp + h;
                const float b2   = sbp2[nt*16 + c16];
                const int   gidx = 2*nt + (c16 >> 3);
                #pragma unroll
                for (int u = 0; u < 2; ++u) {
                    const f32x4 pc  = (h == 0) ? pa[u] : pb[u];
                    const f32x4 swv = *(const f32x4*)(ybuf[w][u] + gidx*16 + quad*4);
                    float a2 = 0.f;
                    #pragma unroll
                    for (int r = 0; r < 4; ++r)
                        a2 = fmaf(pc[r] + b2 + bf2f(va[ntp][h][u][r]), swv[r], a2);
                    a2 += __shfl_xor(a2, 16, 64);
                    a2 += __shfl_xor(a2, 32, 64);
                    if (quad == 0) out[(size_t)(n0 + u)*CC + nt*16 + c16] = a2;
                }
            }
        }

        // rotate prefetched refidx into place for the next iteration
        id[0] = idn[0]; id[1] = idn[1];
        rr[0] = rrn[0]; rr[1] = rrn[1];
    }
}

extern "C" void kernel_launch(void* const* d_in, const int* in_sizes, int n_in,
                              void* d_out, int out_size, void* d_ws, size_t ws_size,
                              hipStream_t stream)
{
    const float* q     = (const float*)d_in[0];
    const float* k     = (const float*)d_in[1];
    const float* v     = (const float*)d_in[2];
    const float* xyz   = (const float*)d_in[3];
    const int*   ridx  = (const int*)d_in[4];
    const float* Wq    = (const float*)d_in[5];
    const float* bq    = (const float*)d_in[6];
    const float* gq    = (const float*)d_in[7];
    const float* betaq = (const float*)d_in[8];
    const float* Wk    = (const float*)d_in[9];
    const float* bk    = (const float*)d_in[10];
    const float* gk    = (const float*)d_in[11];
    const float* betak = (const float*)d_in[12];
    const float* Wv    = (const float*)d_in[13];
    const float* bv    = (const float*)d_in[14];
    const float* Wp1   = (const float*)d_in[15];
    const float* bp1   = (const float*)d_in[16];
    const float* gp    = (const float*)d_in[17];
    const float* betap = (const float*)d_in[18];
    const float* Wp2   = (const float*)d_in[19];
    const float* bp2   = (const float*)d_in[20];
    const float* Ww1   = (const float*)d_in[21];
    const float* bw1   = (const float*)d_in[22];
    const float* gw    = (const float*)d_in[23];
    const float* betaw = (const float*)d_in[24];
    const float* Ww2   = (const float*)d_in[25];
    const float* bw2   = (const float*)d_in[26];
    float* out = (float*)d_out;

    ushort* valw  = (ushort*)d_ws;                       // [N, 96] bf16
    ushort* kw1w  = valw + (size_t)NN*CC;                // [N, 12] bf16
    ushort* qw1w  = kw1w + (size_t)NN*GG;                // [N, 12] bf16
    float* cfused = (float*)(qw1w + (size_t)NN*GG);      // 16   (9.6 MB offset, 16B-aligned)
    float* statsp = cfused + 16;                         // 20 (+pad 4)
    ushort* fragQKV = (ushort*)(statsp + 24);            // 3*9216
    ushort* fragP2  = fragQKV + 3*9216;                  // 9216
    ushort* fragW1  = fragP2 + 9216;                     // 1536
    ushort* fragWf  = fragW1 + 1536;                     // 1536

    prep_kernel<<<dim3(157, 1, 1), 256, 0, stream>>>(
        Wq, Wk, Wv, Wp2, Ww1, bp2, bw1, Wp1, bp1,
        fragQKV, fragP2, fragW1, fragWf, cfused, statsp);

    qkv_mfma<<<dim3(625, 3, 1), 256, 0, stream>>>(
        q, k, v, bq, gq, betaq, bk, gk, betak, bv,
        fragQKV, fragW1, valw, qw1w, kw1w);

    attn2<<<dim3(1280, 1, 1), 256, 0, stream>>>(
        xyz, ridx, gp, betap, Wp1, bp1, bp2,
        gw, betaw, Ww2, bw2, cfused, statsp,
        fragP2, fragWf, valw, kw1w, qw1w, out);
}

// Round 7
// 205.648 us; speedup vs baseline: 1.0931x; 1.0931x over previous
//
#include <hip/hip_runtime.h>

#define NN 40000
#define SS 16
#define CC 96
#define GG 12
#define VKS 128   // vkp row stride in ushorts: 16 groups x {6 val, 1 kw, 1 pad} = 256B/row
#define SXP 104   // ushort stride for qkv transpose buffer: 208 B rows, 16B-aligned frag reads

typedef __attribute__((ext_vector_type(8))) short bf16x8;
typedef __attribute__((ext_vector_type(4))) float f32x4;

// float -> bf16 (RNE), raw 16-bit pattern (prep-path quality)
__device__ __forceinline__ short f2bf(float f) {
    union { float f; unsigned u; } c; c.f = f;
    unsigned r = (c.u + 0x7fffu + ((c.u >> 16) & 1u)) >> 16;
    return (short)r;
}
// pack two floats -> (bf16(hi)<<16)|bf16(lo) in ONE v_perm_b32 (+half-up rounding)
__device__ __forceinline__ unsigned pack2bf(float hi, float lo) {
    unsigned a = __float_as_uint(hi) + 0x8000u;
    unsigned b = __float_as_uint(lo) + 0x8000u;
    return __builtin_amdgcn_perm(a, b, 0x07060302u);
}
// single float -> bf16 (half-up, 2 ops)
__device__ __forceinline__ ushort f2bf_hu(float f) {
    return (ushort)((__float_as_uint(f) + 0x8000u) >> 16);
}
// bf16 (raw ushort) -> float: one shift
__device__ __forceinline__ float bf2f(ushort u) {
    return __uint_as_float(((unsigned)u) << 16);
}

// ---- DPP cross-lane within 16-lane rows (~2 cyc vs ~120 for ds_bpermute) ----
template<int CTRL>
__device__ __forceinline__ float dppf(float x) {
    int r = __builtin_amdgcn_mov_dpp(__float_as_int(x), CTRL, 0xF, 0xF, true);
    return __int_as_float(r);
}
__device__ __forceinline__ float row16_sum(float x) {
    x += dppf<0xB1>(x);    // quad_perm [1,0,3,2]
    x += dppf<0x4E>(x);    // quad_perm [2,3,0,1]
    x += dppf<0x141>(x);   // ROW_HALF_MIRROR
    x += dppf<0x140>(x);   // ROW_MIRROR
    return x;
}
__device__ __forceinline__ float row16_max(float x) {
    x = fmaxf(x, dppf<0xB1>(x));
    x = fmaxf(x, dppf<0x4E>(x));
    x = fmaxf(x, dppf<0x141>(x));
    x = fmaxf(x, dppf<0x140>(x));
    return x;
}

// job-range constants for prep
#define J_W3   27648            // 3 x 9216: Wq/Wk/Wv frags
#define J_P2   (J_W3 + 9216)    // Wp2 frags
#define J_W1   (J_P2 + 1536)    // Ww1 frags (padded to 16 cols)
#define J_WF   (J_W1 + 1536)    // Wfused frags (direct 96-dot)
#define J_CF   (J_WF + 12)      // cfused
#define J_S4   (J_CF + 4)       // s4 = A^T 1
#define J_G    (J_S4 + 16)      // G = A^T A
// grid = ceil(J_G/256) = 157

// ---------------- prep: all weight fragments + LN-stats, once ----------------
__global__ void prep_kernel(const float* __restrict__ Wq, const float* __restrict__ Wk,
                            const float* __restrict__ Wv, const float* __restrict__ Wp2,
                            const float* __restrict__ Ww1, const float* __restrict__ bp2,
                            const float* __restrict__ bw1, const float* __restrict__ Wp1,
                            const float* __restrict__ bp1,
                            ushort* __restrict__ fragQKV, ushort* __restrict__ fragP2,
                            ushort* __restrict__ fragW1, ushort* __restrict__ fragWf,
                            float* __restrict__ cfused, float* __restrict__ stats)
{
    const int job = blockIdx.x*256 + threadIdx.x;
    if (job < J_W3) {
        const int which = job / 9216, o = job % 9216;
        const float* W = (which == 0) ? Wq : (which == 1) ? Wk : Wv;
        const int pos = o >> 3, j = o & 7;
        const int lane = pos & 63, ntkb = pos >> 6;
        const int nt = ntkb / 3, kb = ntkb - nt*3;
        const int col = nt*16 + (lane & 15), krow = kb*32 + (lane >> 4)*8 + j;
        fragQKV[job] = (ushort)f2bf(W[krow*CC + col]);
    } else if (job < J_P2) {
        const int o = job - J_W3;
        const int pos = o >> 3, j = o & 7;
        const int lane = pos & 63, ntkb = pos >> 6;
        const int nt = ntkb / 3, kb = ntkb - nt*3;
        const int col = nt*16 + (lane & 15), krow = kb*32 + (lane >> 4)*8 + j;
        fragP2[o] = (ushort)f2bf(Wp2[krow*CC + col]);
    } else if (job < J_W1) {
        const int o = job - J_P2;
        const int pos = o >> 3, j = o & 7;
        const int lane = pos & 63, kb = pos >> 6;
        const int col = lane & 15, krow = kb*32 + (lane >> 4)*8 + j;
        fragW1[o] = (col < GG) ? (ushort)f2bf(Ww1[krow*GG + col]) : (ushort)0;
    } else if (job < J_WF) {
        const int o = job - J_W1;
        const int pos = o >> 3, j = o & 7;
        const int lane = pos & 63, kb = pos >> 6;
        const int col = lane & 15, krow = kb*32 + (lane >> 4)*8 + j;
        float s = 0.f;
        if (col < GG) for (int jj = 0; jj < CC; ++jj) s += Wp2[krow*CC + jj] * Ww1[jj*GG + col];
        fragWf[o] = (col < GG) ? (ushort)f2bf(s) : (ushort)0;
    } else if (job < J_CF) {
        const int g = job - J_WF;
        float s = bw1[g];
        for (int jj = 0; jj < CC; ++jj) s += bp2[jj] * Ww1[jj*GG + g];
        cfused[g] = s;
    } else if (job < J_S4) {
        const int d = job - J_CF;
        float s = 0.f;
        for (int c = 0; c < CC; ++c) s += (d < 3) ? Wp1[d*CC + c] : bp1[c];
        stats[d] = s;
    } else if (job < J_G) {
        const int o = job - J_S4, d1 = o >> 2, d2 = o & 3;
        float s = 0.f;
        for (int c = 0; c < CC; ++c) {
            const float a1 = (d1 < 3) ? Wp1[d1*CC + c] : bp1[c];
            const float a2 = (d2 < 3) ? Wp1[d2*CC + c] : bp1[c];
            s += a1*a2;
        }
        stats[4 + o] = s;
    }
}

// ---------------- Kernel A: q/k/v projections via MFMA, ONE tile per wave ----------------
// R17: val + kw now written into the PACKED gather array vkp[row][c16*8 + {0..5:val,
// 6:kw, 7:pad}] (256B rows) so attn2's per-neighbor gather is ONE dwordx4 per lane.
// p==3 sub-grid packs xyz -> float4 xyzp. qw1 stays [N][12] bf16.
__global__ __launch_bounds__(256) void qkv_mfma(
    const float* __restrict__ q, const float* __restrict__ kx, const float* __restrict__ v,
    const float* __restrict__ bq, const float* __restrict__ gq, const float* __restrict__ betaq,
    const float* __restrict__ bk, const float* __restrict__ gk, const float* __restrict__ betak,
    const float* __restrict__ bv, const float* __restrict__ xyz,
    const ushort* __restrict__ fragQKV, const ushort* __restrict__ fragW1,
    ushort* __restrict__ vkp, ushort* __restrict__ qw1out, float* __restrict__ xyzp)
{
    const int p = blockIdx.y;
    const int t = threadIdx.x;

    if (p == 3) {   // xyz -> float4 pack: 625 blocks x 64 rows
        const int rrow = blockIdx.x*64 + (t >> 2), c = t & 3;
        xyzp[(size_t)rrow*4 + c] = (c < 3) ? xyz[(size_t)rrow*3 + c] : 0.f;
        return;
    }

    __shared__ float sbias[CC], sg[CC], sbeta[CC];
    __shared__ __align__(16) ushort sx2[4][16*SXP];   // per-wave bf16 transpose buffer

    const float* X; const float* b;
    const float* g = nullptr; const float* beta = nullptr;
    if (p == 0)      { X = q;  b = bq; g = gq; beta = betaq; }
    else if (p == 1) { X = kx; b = bk; g = gk; beta = betak; }
    else             { X = v;  b = bv; }
    const bool has_ln = (p < 2);

    if (t < CC) {
        sbias[t] = b[t];
        if (has_ln) { sg[t] = g[t]; sbeta[t] = beta[t]; }
    }

    const int lane = t & 63, w = t >> 6;
    const int c16 = lane & 15, quad = lane >> 4;
    const ushort* fragW = fragQKV + p*9216;

    bf16x8 Ww1f[3];
    if (has_ln) {
        #pragma unroll
        for (int kb = 0; kb < 3; ++kb) {
            union { bf16x8 v; uint4 u; } wu;
            wu.u = ((const uint4*)fragW1)[kb*64 + lane];
            Ww1f[kb] = wu.v;
        }
    }

    __syncthreads();

    const f32x4 zero4 = {0.f, 0.f, 0.f, 0.f};
    ushort* sxw = sx2[w];
    const int tile = blockIdx.x*4 + w;     // exactly 2500 tiles
    const int row0 = tile * 16;

    const float* xr = X + (size_t)(row0 + c16)*CC;
    bf16x8 Af[3];
    #pragma unroll
    for (int kb = 0; kb < 3; ++kb) {
        const float4 a0 = *(const float4*)(xr + kb*32 + quad*8);
        const float4 a1 = *(const float4*)(xr + kb*32 + quad*8 + 4);
        union { bf16x8 v; uint u[4]; } au;
        au.u[0] = pack2bf(a0.y, a0.x);
        au.u[1] = pack2bf(a0.w, a0.z);
        au.u[2] = pack2bf(a1.y, a1.x);
        au.u[3] = pack2bf(a1.w, a1.z);
        Af[kb] = au.v;
    }

    f32x4 acc[6];
    #pragma unroll
    for (int nt = 0; nt < 6; ++nt) acc[nt] = zero4;
    #pragma unroll
    for (int kb = 0; kb < 3; ++kb)
        #pragma unroll
        for (int nt = 0; nt < 6; ++nt) {
            const bf16x8 bf = *(const bf16x8*)(fragW + ((nt*3 + kb)*64 + lane)*8);
            acc[nt] = __builtin_amdgcn_mfma_f32_16x16x32_bf16(Af[kb], bf, acc[nt], 0, 0, 0);
        }

    #pragma unroll
    for (int nt = 0; nt < 6; ++nt) {
        const float bb = sbias[nt*16 + c16];
        #pragma unroll
        for (int r = 0; r < 4; ++r) acc[nt][r] += bb;
    }

    if (has_ln) {
        #pragma unroll
        for (int r = 0; r < 4; ++r) {
            float sum = 0.f, sq = 0.f;
            #pragma unroll
            for (int nt = 0; nt < 6; ++nt) { float x = acc[nt][r]; sum += x; sq += x*x; }
            sum = row16_sum(sum); sq = row16_sum(sq);
            const float mu  = sum * (1.f/96.f);
            const float var = sq * (1.f/96.f) - mu*mu;
            const float rs  = rsqrtf(var + 1e-5f);
            #pragma unroll
            for (int nt = 0; nt < 6; ++nt) {
                const int c = nt*16 + c16;
                acc[nt][r] = fmaxf((acc[nt][r] - mu)*rs*sg[c] + sbeta[c], 0.f);
            }
        }
        // C/D -> per-wave bf16 LDS -> direct A-frag readback (no repacking)
        #pragma unroll
        for (int nt = 0; nt < 6; ++nt)
            #pragma unroll
            for (int r = 0; r < 4; ++r)
                sxw[(quad*4 + r)*SXP + nt*16 + c16] = f2bf_hu(acc[nt][r]);

        f32x4 o = zero4;
        #pragma unroll
        for (int kb = 0; kb < 3; ++kb) {
            const bf16x8 aA = *(const bf16x8*)(sxw + c16*SXP + kb*32 + quad*8);
            o = __builtin_amdgcn_mfma_f32_16x16x32_bf16(aA, Ww1f[kb], o, 0, 0, 0);
        }
        if (c16 < GG) {
            #pragma unroll
            for (int r = 0; r < 4; ++r) {
                if (p == 0)
                    qw1out[(size_t)(row0 + quad*4 + r)*GG + c16] = (ushort)f2bf(o[r]);
                else
                    vkp[(size_t)(row0 + quad*4 + r)*VKS + c16*8 + 6] = (ushort)f2bf(o[r]);
            }
        }
    } else {
        // val path: packed write [row][c16*8 + nt]; zero the pad and (c16>=12) kw slot
        #pragma unroll
        for (int r = 0; r < 4; ++r) {
            ushort* dst = vkp + (size_t)(row0 + quad*4 + r)*VKS + c16*8;
            #pragma unroll
            for (int nt = 0; nt < 6; ++nt) dst[nt] = (ushort)f2bf(acc[nt][r]);
            dst[7] = 0;
            if (c16 >= GG) dst[6] = 0;
        }
    }
}

// ---------------- Kernel B: grouped vector attention, TWO nodes per wave ----------------
// R17: address-throughput diagnosis — bytes fell 2x (R14/R16) with time flat; VALU/ILP/
// vmcnt/occupancy changes all flat. The invariant is divergent gather LANE-ADDRESS count
// (~2400/node); TA processes a few addrs/cyc/CU -> ~40-75 µs floor. Fix: packed vkp rows
// put {6 val cols, kw} for (row,c16) in ONE 16B slot -> one dwordx4 gather per (u,r):
// 56 -> 8 gather instrs per wave (7x fewer lane-addrs), landing in consumption layout.
// xyz gathers via float4 xyzp (3 instr -> 1). Non-persistent grid 5000 (best measured).
// Issue order: [refidx,Wff,qv,cx] -> [sx, vk] -> SB -> compute (kw consumed phase 4 so
// vk must be old by then; no loads after vk, so no FIFO inversion possible).
__global__ __launch_bounds__(256) void attn2(
    const float4* __restrict__ xyzp, const int* __restrict__ refidx,
    const float* __restrict__ gp,  const float* __restrict__ betap,
    const float* __restrict__ Wp1, const float* __restrict__ bp1,
    const float* __restrict__ bp2,
    const float* __restrict__ gw,  const float* __restrict__ betaw,
    const float* __restrict__ Ww2, const float* __restrict__ bw2,
    const float* __restrict__ cfused, const float* __restrict__ stats,
    const ushort* __restrict__ fragP2, const ushort* __restrict__ fragWf,
    const ushort* __restrict__ vkp, const ushort* __restrict__ qw1w,
    float* __restrict__ out)
{
    __shared__ __align__(16) ushort sWp2f[9216];   // Wp2 B-frags, 18 KB
    __shared__ float4 sA[CC];                      // (Wp1 row0, row1, row2, bp1) per col
    __shared__ float2 sGB[CC];                     // (gp, betap) per col
    __shared__ float  sbp2[CC];
    __shared__ __align__(16) float sWw2T[GG*GG];   // Ww2 TRANSPOSED: [g'][g], 48B rows 16B-aligned
    __shared__ float  sgw[16], sbetaw[16], sbw2[16], scf[16];
    __shared__ float  sstats[20];
    __shared__ __align__(16) float ybuf[4][2][SS*GG]; // per wave, per node: yb then sw2 (aliased)

    const int t = threadIdx.x;
    if (t < CC) {
        sA[t]  = make_float4(Wp1[t], Wp1[CC + t], Wp1[2*CC + t], bp1[t]);
        sGB[t] = make_float2(gp[t], betap[t]);
        sbp2[t] = bp2[t];
    }
    if (t < GG*GG) {
        const int gr = t / GG, gc = t - gr*GG;     // Ww2[gr][gc]
        sWw2T[gc*GG + gr] = Ww2[t];
    }
    if (t < 16) {
        sgw[t]    = (t < GG) ? gw[t]     : 0.f;
        sbetaw[t] = (t < GG) ? betaw[t]  : 0.f;
        sbw2[t]   = (t < GG) ? bw2[t]    : 0.f;
        scf[t]    = (t < GG) ? cfused[t] : 0.f;
    }
    if (t < 20) sstats[t] = stats[t];
    for (int i = t; i < 1152; i += 256) ((uint4*)sWp2f)[i] = ((const uint4*)fragP2)[i];

    const int lane = t & 63, w = t >> 6;
    const int c16 = lane & 15, quad = lane >> 4;
    const int gcl = (c16 < GG) ? c16 : (GG-1);
    const float laneg = (c16 < GG) ? 1.f : 0.f;

    __syncthreads();   // staging done; below is wave-synchronous

    const f32x4 zero4 = {0.f, 0.f, 0.f, 0.f};
    const int n0 = blockIdx.x*8 + w*2;   // two nodes per wave: n0, n0+1

    // ==== ISSUE GROUP 1 (oldest): refidx (gates group 2) + static-address loads
    int   id[2];  int4 rr[2];
    #pragma unroll
    for (int u = 0; u < 2; ++u) {
        id[u] = refidx[(size_t)(n0 + u)*SS + c16];
        rr[u] = *(const int4*)(refidx + (size_t)(n0 + u)*SS + quad*4);
    }
    ushort qvu[2];
    #pragma unroll
    for (int u = 0; u < 2; ++u) qvu[u] = qw1w[(size_t)(n0 + u)*GG + gcl];
    float4 cx[2];
    #pragma unroll
    for (int u = 0; u < 2; ++u) cx[u] = xyzp[n0 + u];
    bf16x8 Wff[3];
    #pragma unroll
    for (int kb = 0; kb < 3; ++kb) {
        union { bf16x8 v; uint4 u; } wu;
        wu.u = ((const uint4*)fragWf)[kb*64 + lane];
        Wff[kb] = wu.v;
    }

    // ---- consume refidx (waits only refidx; rest stays in flight) ----
    float mm[2]; int safe1[2];
    #pragma unroll
    for (int u = 0; u < 2; ++u) {
        mm[u]    = (id[u] >= 0) ? 1.f : 0.f;
        safe1[u] = (id[u] < 0) ? 0 : id[u];
    }
    int sid[2][4]; float mrg[2][4];
    #pragma unroll
    for (int u = 0; u < 2; ++u) {
        const int rv0 = rr[u].x, rv1 = rr[u].y, rv2 = rr[u].z, rv3 = rr[u].w;
        sid[u][0] = (rv0 < 0) ? 0 : rv0;  mrg[u][0] = (rv0 >= 0) ? 1.f : 0.f;
        sid[u][1] = (rv1 < 0) ? 0 : rv1;  mrg[u][1] = (rv1 >= 0) ? 1.f : 0.f;
        sid[u][2] = (rv2 < 0) ? 0 : rv2;  mrg[u][2] = (rv2 >= 0) ? 1.f : 0.f;
        sid[u][3] = (rv3 < 0) ? 0 : rv3;  mrg[u][3] = (rv3 >= 0) ? 1.f : 0.f;
    }

    // ==== ISSUE GROUP 2: safe-xyz (consumed first) then the 8 packed vk gathers.
    // Masked rows load row 0 — val masked by softmax weight 0, kw by mrg 0.
    float4 sx[2];
    #pragma unroll
    for (int u = 0; u < 2; ++u) sx[u] = xyzp[safe1[u]];
    bf16x8 vk[2][4];
    #pragma unroll
    for (int u = 0; u < 2; ++u)
        #pragma unroll
        for (int r = 0; r < 4; ++r)
            vk[u][r] = *(const bf16x8*)(vkp + (size_t)sid[u][r]*VKS + c16*8);

    // PIN: compute below may not hoist above; loads may not sink.
    __builtin_amdgcn_sched_barrier(0);

    // ---- px (waits sx; vk still in flight until phase 4) ----
    float px[2], py[2], pz[2];
    #pragma unroll
    for (int u = 0; u < 2; ++u) {
        px[u] = (sx[u].x - cx[u].x) * mm[u];
        py[u] = (sx[u].y - cx[u].y) * mm[u];
        pz[u] = (sx[u].z - cx[u].z) * mm[u];
    }

    // ==== phase 2: analytic LN stats for both nodes (shared sstats reads) ====
    float muv[2], rsv[2];
    {
        const float s0 = sstats[0], s1 = sstats[1], s2 = sstats[2], s3 = sstats[3];
        float G_[16];
        #pragma unroll
        for (int i = 0; i < 16; ++i) G_[i] = sstats[4 + i];
        #pragma unroll
        for (int u = 0; u < 2; ++u) {
            muv[u] = (px[u]*s0 + py[u]*s1 + pz[u]*s2 + s3) * (1.f/96.f);
            const float p4[4] = {px[u], py[u], pz[u], 1.f};
            float e2 = 0.f;
            #pragma unroll
            for (int a = 0; a < 4; ++a) {
                float ta = 0.f;
                #pragma unroll
                for (int b2 = 0; b2 < 4; ++b2) ta = fmaf(G_[a*4 + b2], p4[b2], ta);
                e2 = fmaf(p4[a], ta, e2);
            }
            const float var = e2*(1.f/96.f) - muv[u]*muv[u];
            rsv[u] = rsqrtf(var + 1e-5f);
        }
    }

    // ==== phase 3: t1A for both nodes; per-column consts loaded ONCE ====
    bf16x8 t1A[2][3];
    #pragma unroll
    for (int kb = 0; kb < 3; ++kb) {
        uint tw[2][4];
        #pragma unroll
        for (int jp = 0; jp < 4; ++jp) {
            const int c0 = kb*32 + quad*8 + jp*2, c1 = c0 + 1;
            const float4 aw0 = sA[c0], aw1 = sA[c1];
            const float2 gb0 = sGB[c0], gb1 = sGB[c1];
            #pragma unroll
            for (int u = 0; u < 2; ++u) {
                const float x0 = fmaf(px[u], aw0.x, fmaf(py[u], aw0.y, fmaf(pz[u], aw0.z, aw0.w)));
                const float x1 = fmaf(px[u], aw1.x, fmaf(py[u], aw1.y, fmaf(pz[u], aw1.z, aw1.w)));
                const float t0 = fmaxf(fmaf((x0 - muv[u])*rsv[u], gb0.x, gb0.y), 0.f);
                const float t1v = fmaxf(fmaf((x1 - muv[u])*rsv[u], gb1.x, gb1.y), 0.f);
                tw[u][jp] = pack2bf(t1v, t0);
            }
        }
        #pragma unroll
        for (int u = 0; u < 2; ++u) {
            union { bf16x8 v; uint uu[4]; } tc;
            tc.uu[0] = tw[u][0]; tc.uu[1] = tw[u][1];
            tc.uu[2] = tw[u][2]; tc.uu[3] = tw[u][3];
            t1A[u][kb] = tc.v;
        }
    }

    // ==== phase 4: t2 = t1 @ Wfused; then + kw (vk elem 6) - qw + cfused ====
    f32x4 t2[2];
    #pragma unroll
    for (int u = 0; u < 2; ++u) t2[u] = zero4;
    #pragma unroll
    for (int kb = 0; kb < 3; ++kb)
        #pragma unroll
        for (int u = 0; u < 2; ++u)
            t2[u] = __builtin_amdgcn_mfma_f32_16x16x32_bf16(t1A[u][kb], Wff[kb], t2[u], 0, 0, 0);
    {
        const float cf = scf[c16];
        #pragma unroll
        for (int u = 0; u < 2; ++u) {
            const float qz = bf2f(qvu[u])*laneg;
            #pragma unroll
            for (int r = 0; r < 4; ++r)
                t2[u][r] += bf2f((ushort)vk[u][r][6])*mrg[u][r] - qz + cf;
        }
    }

    // ==== phase 5: LN over G=12 via DPP; both chains interleave ====
    {
        const float gwv = sgw[c16], bwv = sbetaw[c16];
        #pragma unroll
        for (int u = 0; u < 2; ++u) {
            float* yb = ybuf[w][u];
            #pragma unroll
            for (int r = 0; r < 4; ++r) {
                const float x = t2[u][r];          // exact 0 on c16>=12 lanes
                const float s1 = row16_sum(x);
                const float s2 = row16_sum(x*x);
                const float mu2  = s1 * (1.f/12.f);
                const float var2 = s2 * (1.f/12.f) - mu2*mu2;
                const float rs2  = rsqrtf(var2 + 1e-5f);
                const float y    = fmaxf((x - mu2)*rs2*gwv + bwv, 0.f);
                if (c16 < GG) yb[(quad*4 + r)*GG + c16] = y;
            }
        }
    }

    // ==== phase 6: w3 = y @ Ww2 + bw2; Ww2T rows loaded ONCE for both nodes ====
    float w3v[2][3];
    {
        f32x4 yr[2][3];
        #pragma unroll
        for (int u = 0; u < 2; ++u) {
            yr[u][0] = *(const f32x4*)(ybuf[w][u] + c16*GG + 0);
            yr[u][1] = *(const f32x4*)(ybuf[w][u] + c16*GG + 4);
            yr[u][2] = *(const f32x4*)(ybuf[w][u] + c16*GG + 8);
        }
        #pragma unroll
        for (int gi = 0; gi < 3; ++gi) {
            const int gpp = quad + gi*4;
            const f32x4 wa = *(const f32x4*)(sWw2T + gpp*GG + 0);
            const f32x4 wb = *(const f32x4*)(sWw2T + gpp*GG + 4);
            const f32x4 wc = *(const f32x4*)(sWw2T + gpp*GG + 8);
            const float bb = sbw2[gpp];
            #pragma unroll
            for (int u = 0; u < 2; ++u) {
                float a2 = bb;
                #pragma unroll
                for (int j = 0; j < 4; ++j) a2 = fmaf(yr[u][0][j], wa[j], a2);
                #pragma unroll
                for (int j = 0; j < 4; ++j) a2 = fmaf(yr[u][1][j], wb[j], a2);
                #pragma unroll
                for (int j = 0; j < 4; ++j) a2 = fmaf(yr[u][2][j], wc[j], a2);
                w3v[u][gi] = a2;
            }
        }
    }

    // ==== phase 7: softmax over s (DPP) + transposed store sw2[g'][s] ====
    #pragma unroll
    for (int u = 0; u < 2; ++u) {
        #pragma unroll
        for (int gi = 0; gi < 3; ++gi) {
            const float mx = row16_max(w3v[u][gi]);
            const float e  = __expf(w3v[u][gi] - mx);
            const float tot = row16_sum(e);
            w3v[u][gi] = e * __builtin_amdgcn_rcpf(tot) * mm[u];
        }
        float* sw2 = ybuf[w][u];   // aliased with yb: all yb reads above are done
        #pragma unroll
        for (int gi = 0; gi < 3; ++gi)
            sw2[(quad + 4*gi)*16 + c16] = w3v[u][gi];
    }

    // ==== phase 8: merged epilogue; val = vk elem (2*ntp+h), already in-lane ====
    #pragma unroll
    for (int ntp = 0; ntp < 3; ++ntp) {
        const int nt0 = 2*ntp, nt1 = 2*ntp + 1;
        f32x4 pa[2], pb[2];
        #pragma unroll
        for (int u = 0; u < 2; ++u) { pa[u] = zero4; pb[u] = zero4; }
        #pragma unroll
        for (int kb = 0; kb < 3; ++kb) {
            const bf16x8 bfa = *(const bf16x8*)(sWp2f + ((nt0*3 + kb)*64 + lane)*8);
            const bf16x8 bfb = *(const bf16x8*)(sWp2f + ((nt1*3 + kb)*64 + lane)*8);
            #pragma unroll
            for (int u = 0; u < 2; ++u) {
                pa[u] = __builtin_amdgcn_mfma_f32_16x16x32_bf16(t1A[u][kb], bfa, pa[u], 0, 0, 0);
                pb[u] = __builtin_amdgcn_mfma_f32_16x16x32_bf16(t1A[u][kb], bfb, pb[u], 0, 0, 0);
            }
        }
        #pragma unroll
        for (int h = 0; h < 2; ++h) {
            const int nt = 2*ntp + h;
            const float b2   = sbp2[nt*16 + c16];
            const int   gidx = 2*nt + (c16 >> 3);
            #pragma unroll
            for (int u = 0; u < 2; ++u) {
                const f32x4 pc  = (h == 0) ? pa[u] : pb[u];
                const f32x4 swv = *(const f32x4*)(ybuf[w][u] + gidx*16 + quad*4);
                float a2 = 0.f;
                #pragma unroll
                for (int r = 0; r < 4; ++r)
                    a2 = fmaf(pc[r] + b2 + bf2f((ushort)vk[u][r][nt]), swv[r], a2);
                a2 += __shfl_xor(a2, 16, 64);
                a2 += __shfl_xor(a2, 32, 64);
                if (quad == 0) out[(size_t)(n0 + u)*CC + nt*16 + c16] = a2;
            }
        }
    }
}

extern "C" void kernel_launch(void* const* d_in, const int* in_sizes, int n_in,
                              void* d_out, int out_size, void* d_ws, size_t ws_size,
                              hipStream_t stream)
{
    const float* q     = (const float*)d_in[0];
    const float* k     = (const float*)d_in[1];
    const float* v     = (const float*)d_in[2];
    const float* xyz   = (const float*)d_in[3];
    const int*   ridx  = (const int*)d_in[4];
    const float* Wq    = (const float*)d_in[5];
    const float* bq    = (const float*)d_in[6];
    const float* gq    = (const float*)d_in[7];
    const float* betaq = (const float*)d_in[8];
    const float* Wk    = (const float*)d_in[9];
    const float* bk    = (const float*)d_in[10];
    const float* gk    = (const float*)d_in[11];
    const float* betak = (const float*)d_in[12];
    const float* Wv    = (const float*)d_in[13];
    const float* bv    = (const float*)d_in[14];
    const float* Wp1   = (const float*)d_in[15];
    const float* bp1   = (const float*)d_in[16];
    const float* gp    = (const float*)d_in[17];
    const float* betap = (const float*)d_in[18];
    const float* Wp2   = (const float*)d_in[19];
    const float* bp2   = (const float*)d_in[20];
    const float* Ww1   = (const float*)d_in[21];
    const float* bw1   = (const float*)d_in[22];
    const float* gw    = (const float*)d_in[23];
    const float* betaw = (const float*)d_in[24];
    const float* Ww2   = (const float*)d_in[25];
    const float* bw2   = (const float*)d_in[26];
    float* out = (float*)d_out;

    ushort* vkp   = (ushort*)d_ws;                       // [N][128] ush = 10.24 MB
    ushort* qw1w  = vkp + (size_t)NN*VKS;                // [N][12] bf16 = 0.96 MB
    float*  xyzp  = (float*)(qw1w + (size_t)NN*GG);      // [N][4] f32 = 0.64 MB (16B-aligned)
    float* cfused = xyzp + (size_t)NN*4;                 // 16
    float* statsp = cfused + 16;                         // 20 (+pad 4)
    ushort* fragQKV = (ushort*)(statsp + 24);            // 3*9216
    ushort* fragP2  = fragQKV + 3*9216;                  // 9216
    ushort* fragW1  = fragP2 + 9216;                     // 1536
    ushort* fragWf  = fragW1 + 1536;                     // 1536

    prep_kernel<<<dim3(157, 1, 1), 256, 0, stream>>>(
        Wq, Wk, Wv, Wp2, Ww1, bp2, bw1, Wp1, bp1,
        fragQKV, fragP2, fragW1, fragWf, cfused, statsp);

    qkv_mfma<<<dim3(625, 4, 1), 256, 0, stream>>>(
        q, k, v, bq, gq, betaq, bk, gk, betak, bv, xyz,
        fragQKV, fragW1, vkp, qw1w, xyzp);

    attn2<<<dim3(5000, 1, 1), 256, 0, stream>>>(
        (const float4*)xyzp, ridx, gp, betap, Wp1, bp1, bp2,
        gw, betaw, Ww2, bw2, cfused, statsp,
        fragP2, fragWf, vkp, qw1w, out);
}